// Round 1
// baseline (749.592 us; speedup 1.0000x reference)
//
#include <hip/hip_runtime.h>
#include <hip/hip_cooperative_groups.h>
#include <math.h>

namespace cg = cooperative_groups;

#define NP 48   // 16 batch * 3 channels

typedef float v2f __attribute__((ext_vector_type(2)));

__device__ __forceinline__ float uniform_f(float v) {
    int i = __builtin_amdgcn_readfirstlane(__builtin_bit_cast(int, v));
    return __builtin_bit_cast(float, i);
}

// ---------------- sliding-window SSIM strip ----------------
// R output rows per lane, EXACT step count R+10 = CHF*22 + TAIL (no dead steps).
// 1-step register prefetch: loads for row rr+1 issue unconditionally (clamped
// address) before the compute of row rr.
template<int CHF, int TAIL, int R>
__device__ __forceinline__ void ssim_scale(
        const float* __restrict__ P, const float* __restrict__ T,
        int H, int sh, int lb, int scale, int slotsel, int tid,
        const float* __restrict__ k2d, double* __restrict__ accum)
{
    // normalized 1D gaussian from center row of 2D kernel, pinned to SGPRs
    float w[11];
    {
        float s = 0.f;
#pragma unroll
        for (int i = 0; i < 11; ++i) s += k2d[55 + i];
        float inv = 1.0f / s;
#pragma unroll
        for (int i = 0; i < 11; ++i) w[i] = uniform_f(k2d[55 + i] * inv);
    }

    int blocksX = (NP << sh) >> 8;          // 48*H / 256
    int bxi = lb % blocksX;
    int by  = lb / blocksX;
    int g   = (bxi << 8) + tid;
    int pl  = g >> sh;
    int x   = g & (H - 1);
    int yb  = by * R;

    // per-lane clamped window base + edge-zeroed weights (zero-pad semantics)
    int bcl = x - 5;
    bcl = bcl < 0 ? 0 : bcl;
    bcl = bcl > H - 11 ? H - 11 : bcl;
    int d = bcl - (x - 5);                  // in [-5, 5]; 0 interior
    float wc[11];
#pragma unroll
    for (int j = 0; j < 11; ++j) {
        int idx = j + d;
        float val = 0.f;
#pragma unroll
        for (int i = 0; i < 11; ++i) val = (idx == i) ? w[i] : val;
        wc[j] = val;
    }

    const float* Pb = P + (size_t)pl * H * H + bcl;
    const float* Tb = T + (size_t)pl * H * H + bcl;

    v2f tap[2][11];                         // raw {p,t} taps, double-buffered
    v2f wmu[11], we[11];
    float wpt[11];
    const float C1 = 1e-4f, C2 = 9e-4f;
    float lsum = 0.f, csum = 0.f;
    int rr = yb - 5;                        // compute row of step 0

    // preload step-0 row (clamped; vertical zero-pad handled by rr<0 guard)
    {
        int cr = rr < 0 ? 0 : rr;
        const float* rp = Pb + (size_t)cr * H;
        const float* rt = Tb + (size_t)cr * H;
#pragma unroll
        for (int j = 0; j < 11; ++j) tap[0][j] = (v2f){rp[j], rt[j]};
    }

#define SSIM_STEP(PH)                                                          \
    {                                                                          \
        const int cb = (PH) & 1;            /* compile-time buffer parity */   \
        const int sl = (PH) % 11;           /* compile-time window slot   */   \
        {   /* branchless prefetch of row rr+1 into tap[cb^1] */               \
            int nr = rr + 1;                                                   \
            nr = nr < 0 ? 0 : nr;                                              \
            nr = nr > H - 1 ? H - 1 : nr;                                      \
            const float* rp = Pb + (size_t)nr * H;                             \
            const float* rt = Tb + (size_t)nr * H;                             \
            _Pragma("unroll")                                                  \
            for (int j = 0; j < 11; ++j) tap[cb ^ 1][j] = (v2f){rp[j], rt[j]}; \
        }                                                                      \
        v2f a_mu = (v2f){0.f, 0.f};                                            \
        v2f a_e  = (v2f){0.f, 0.f};                                            \
        v2f a_pt = (v2f){0.f, 0.f};                                            \
        if (rr >= 0 && rr < H) {            /* uniform; taps in registers */   \
            _Pragma("unroll")                                                  \
            for (int j = 0; j < 11; ++j) {                                     \
                v2f pt2 = tap[cb][j];                                          \
                v2f wv  = (v2f){wc[j], wc[j]};                                 \
                v2f wp2 = wv * pt2;                                            \
                v2f ptr2 = (v2f){pt2.y, pt2.x};                                \
                a_mu += wp2;                                                   \
                a_e  += wp2 * pt2;                                             \
                a_pt += wp2 * ptr2;         /* halves: wp*t , wt*p */          \
            }                                                                  \
        }                                                                      \
        wmu[sl] = a_mu; we[sl] = a_e;                                          \
        wpt[sl] = a_pt.x + a_pt.y;          /* = 2*sum(w p t) */               \
        if (rr >= yb + 5) {                 /* emit output row rr-5 */         \
            v2f mu2 = (v2f){0.f, 0.f};                                         \
            v2f e2  = (v2f){0.f, 0.f};                                         \
            float ept = 0.f;                                                   \
            _Pragma("unroll")                                                  \
            for (int i = 0; i < 11; ++i) {                                     \
                const int ss = (sl + 1 + i) % 11;   /* compile-time */         \
                v2f wi = (v2f){w[i], w[i]};         /* SGPR broadcast */       \
                mu2 += wi * wmu[ss];                                           \
                e2  += wi * we[ss];                                            \
                ept += w[i] * wpt[ss];                                         \
            }                                                                  \
            float m11 = mu2.x * mu2.x, m22 = mu2.y * mu2.y, m12 = mu2.x * mu2.y; \
            float s1  = fmaxf(e2.x - m11, 0.f);                                \
            float s2  = fmaxf(e2.y - m22, 0.f);                                \
            float s12 = 0.5f * ept - m12;                                      \
            lsum += (2.f * m12 + C1) * __builtin_amdgcn_rcpf(m11 + m22 + C1);  \
            csum += (2.f * s12 + C2) * __builtin_amdgcn_rcpf(s1 + s2 + C2);    \
        }                                                                      \
        rr++;                                                                  \
    }

#pragma unroll 1
    for (int ch = 0; ch < CHF; ++ch) {
#pragma unroll
        for (int ph = 0; ph < 22; ++ph) SSIM_STEP(ph)
    }
#pragma unroll
    for (int ph = 0; ph < TAIL; ++ph) SSIM_STEP(ph)
#undef SSIM_STEP

    // wave shuffle reduce then cross-wave via LDS
#pragma unroll
    for (int o = 32; o > 0; o >>= 1) {
        lsum += __shfl_down(lsum, o, 64);
        csum += __shfl_down(csum, o, 64);
    }
    __shared__ float red[8];
    int wv = tid >> 6;
    if ((tid & 63) == 0) { red[2 * wv] = lsum; red[2 * wv + 1] = csum; }
    __syncthreads();
    if (tid == 0) {
        int slot = (scale * 8 + slotsel) * 2;
        atomicAdd(&accum[slot],     (double)(red[0] + red[2] + red[4] + red[6]));
        atomicAdd(&accum[slot + 1], (double)(red[1] + red[3] + red[5] + red[7]));
    }
    __syncthreads();    // protect red[] against next grid-stride job
}

// ---------------- pool job: 64x64 s1 tile; all scales from s0 ----------------
__device__ __forceinline__ void pool_job(int b, int tid,
        const float* __restrict__ pred, const float* __restrict__ targ,
        float* __restrict__ p1, float* __restrict__ t1,
        float* __restrict__ p2, float* __restrict__ t2,
        float* __restrict__ p3, float* __restrict__ t3,
        float* __restrict__ p4, float* __restrict__ t4)
{
    int pi   = b >> 4;          // 0..95 plane-image
    int tile = b & 15;          // 4x4 tiles over the 256x256 s1 plane
    int pls  = pi < 48 ? pi : pi - 48;
    const float* src = (pi < 48 ? pred : targ) + (size_t)pls * 512 * 512;
    float* d1 = (pi < 48 ? p1 : t1) + (size_t)pls * 256 * 256;
    float* d2 = (pi < 48 ? p2 : t2) + (size_t)pls * 128 * 128;
    float* d3 = (pi < 48 ? p3 : t3) + (size_t)pls * 64 * 64;
    float* d4 = (pi < 48 ? p4 : t4) + (size_t)pls * 32 * 32;
    int tY = tile >> 2, tX = tile & 3;
    int ty = tid >> 4, tx = tid & 15;
    int gy0 = tY * 128 + ty * 8, gx0 = tX * 128 + tx * 8;

    float s1v[4][4];
#pragma unroll
    for (int i = 0; i < 4; ++i) {
        const float* r0 = src + (size_t)(gy0 + 2 * i) * 512 + gx0;
        const float* r1 = r0 + 512;
        float4 a0 = *(const float4*)r0, a1 = *(const float4*)(r0 + 4);
        float4 b0 = *(const float4*)r1, b1 = *(const float4*)(r1 + 4);
        s1v[i][0] = 0.25f * ((a0.x + a0.y) + (b0.x + b0.y));
        s1v[i][1] = 0.25f * ((a0.z + a0.w) + (b0.z + b0.w));
        s1v[i][2] = 0.25f * ((a1.x + a1.y) + (b1.x + b1.y));
        s1v[i][3] = 0.25f * ((a1.z + a1.w) + (b1.z + b1.w));
        *(float4*)(d1 + (size_t)(tY * 64 + ty * 4 + i) * 256 + tX * 64 + tx * 4) =
            *(float4*)s1v[i];
    }
    float s2v[2][2];
#pragma unroll
    for (int i = 0; i < 2; ++i) {
#pragma unroll
        for (int j = 0; j < 2; ++j)
            s2v[i][j] = 0.25f * ((s1v[2*i][2*j] + s1v[2*i][2*j+1]) +
                                 (s1v[2*i+1][2*j] + s1v[2*i+1][2*j+1]));
        *(float2*)(d2 + (size_t)(tY * 32 + ty * 2 + i) * 128 + tX * 32 + tx * 2) =
            *(float2*)s2v[i];
    }
    float s3 = 0.25f * ((s2v[0][0] + s2v[0][1]) + (s2v[1][0] + s2v[1][1]));
    d3[(size_t)(tY * 16 + ty) * 64 + tX * 16 + tx] = s3;
    float v1 = s3 + __shfl_xor(s3, 1, 64);
    float v2 = v1 + __shfl_xor(v1, 16, 64);
    if ((ty & 1) == 0 && (tx & 1) == 0)
        d4[(size_t)(tY * 8 + (ty >> 1)) * 32 + tX * 8 + (tx >> 1)] = 0.25f * v2;
}

// ---------------- unified ssim job dispatch (1026 equal-cost jobs) ----------------
// 64-row strips: scale0=768, scale1=192, scale2=48, scale3=12; scale4 (H=32)=6 strips.
__device__ __forceinline__ void ssim_dispatch(int j, int tid,
        const float* __restrict__ pred, const float* __restrict__ targ,
        const float* __restrict__ p1, const float* __restrict__ t1,
        const float* __restrict__ p2, const float* __restrict__ t2,
        const float* __restrict__ p3, const float* __restrict__ t3,
        const float* __restrict__ p4, const float* __restrict__ t4,
        const float* __restrict__ k2d, double* __restrict__ accum)
{
    if (j < 1020) {
        const float *P, *T; int H, sh, lb, scale;
        if (j < 768)       { P = pred; T = targ; H = 512; sh = 9; lb = j;        scale = 0; }
        else if (j < 960)  { P = p1;   T = t1;   H = 256; sh = 8; lb = j - 768;  scale = 1; }
        else if (j < 1008) { P = p2;   T = t2;   H = 128; sh = 7; lb = j - 960;  scale = 2; }
        else               { P = p3;   T = t3;   H = 64;  sh = 6; lb = j - 1008; scale = 3; }
        ssim_scale<3, 8, 64>(P, T, H, sh, lb, scale, j & 7, tid, k2d, accum);
    } else {
        ssim_scale<1, 20, 32>(p4, t4, 32, 5, j - 1020, 4, j & 7, tid, k2d, accum);
    }
}

// ---------------- finalize: weighted power product ----------------
__device__ void finalize(const double* __restrict__ accum, float* __restrict__ out) {
    const float wts[5] = {0.0448f, 0.2856f, 0.3001f, 0.2363f, 0.1333f};
    float ms = 1.0f;
    int Hs = 512;
    for (int s = 0; s < 5; ++s) {
        double lt = 0.0, ct = 0.0;
        for (int k = 0; k < 8; ++k) {
            lt += accum[(s * 8 + k) * 2];
            ct += accum[(s * 8 + k) * 2 + 1];
        }
        float N  = 48.0f * (float)Hs * (float)Hs;
        float l  = (float)lt / N;
        float cs = fmaxf((float)ct / N, 1e-8f);
        if (s == 4) {
            l = fmaxf(l, 1e-8f);
            ms *= powf(l, wts[s]) * powf(cs, wts[s]);
        } else {
            ms *= powf(cs, wts[s]);
        }
        Hs >>= 1;
    }
    out[0] = ms;
}

// ---------------- fused cooperative kernel ----------------
// Phase 1: pools (BW-bound, ~25us) -> grid.sync -> Phase 2: all ssim strips,
// balanced 1026 jobs over 1024 co-resident blocks -> grid.sync -> finalize.
__global__ __launch_bounds__(256, 4) void k_fused(
        const float* __restrict__ pred, const float* __restrict__ targ,
        float* __restrict__ p1, float* __restrict__ t1,
        float* __restrict__ p2, float* __restrict__ t2,
        float* __restrict__ p3, float* __restrict__ t3,
        float* __restrict__ p4, float* __restrict__ t4,
        const float* __restrict__ k2d, double* __restrict__ accum,
        float* __restrict__ out)
{
    int tid = threadIdx.x;
    if (blockIdx.x == 0 && tid < 80) accum[tid] = 0.0;   // replaces memset
    for (int j = blockIdx.x; j < 1536; j += gridDim.x)
        pool_job(j, tid, pred, targ, p1, t1, p2, t2, p3, t3, p4, t4);
    cg::this_grid().sync();
    for (int j = blockIdx.x; j < 1026; j += gridDim.x)
        ssim_dispatch(j, tid, pred, targ, p1, t1, p2, t2, p3, t3, p4, t4, k2d, accum);
    cg::this_grid().sync();
    if (blockIdx.x == 0 && tid == 0) finalize(accum, out);
}

// ---------------- non-cooperative fallback path ----------------
__global__ __launch_bounds__(256) void k_pool(
        const float* __restrict__ pred, const float* __restrict__ targ,
        float* __restrict__ p1, float* __restrict__ t1,
        float* __restrict__ p2, float* __restrict__ t2,
        float* __restrict__ p3, float* __restrict__ t3,
        float* __restrict__ p4, float* __restrict__ t4,
        double* __restrict__ accum)
{
    int tid = threadIdx.x;
    if (blockIdx.x == 0 && tid < 80) accum[tid] = 0.0;
    pool_job(blockIdx.x, tid, pred, targ, p1, t1, p2, t2, p3, t3, p4, t4);
}

__global__ __launch_bounds__(256) void k_ssim_all(
        const float* __restrict__ pred, const float* __restrict__ targ,
        const float* __restrict__ p1, const float* __restrict__ t1,
        const float* __restrict__ p2, const float* __restrict__ t2,
        const float* __restrict__ p3, const float* __restrict__ t3,
        const float* __restrict__ p4, const float* __restrict__ t4,
        const float* __restrict__ k2d, double* __restrict__ accum)
{
    ssim_dispatch(blockIdx.x, threadIdx.x, pred, targ, p1, t1, p2, t2, p3, t3,
                  p4, t4, k2d, accum);
}

__global__ void k_final(const double* __restrict__ accum, float* __restrict__ out) {
    if (threadIdx.x != 0 || blockIdx.x != 0) return;
    finalize(accum, out);
}

extern "C" void kernel_launch(void* const* d_in, const int* in_sizes, int n_in,
                              void* d_out, int out_size, void* d_ws, size_t ws_size,
                              hipStream_t stream) {
    const float* pred = (const float*)d_in[0];
    const float* targ = (const float*)d_in[1];
    const float* kern = (const float*)d_in[2];
    float* out = (float*)d_out;

    char* ws = (char*)d_ws;
    double* accum = (double*)ws;             // 80 doubles (5 scales * 8 slots * 2)
    size_t off = 1024;
    float* p1 = (float*)(ws + off); off += (size_t)NP * 256 * 256 * 4;
    float* t1 = (float*)(ws + off); off += (size_t)NP * 256 * 256 * 4;
    float* p2 = (float*)(ws + off); off += (size_t)NP * 128 * 128 * 4;
    float* t2 = (float*)(ws + off); off += (size_t)NP * 128 * 128 * 4;
    float* p3 = (float*)(ws + off); off += (size_t)NP * 64 * 64 * 4;
    float* t3 = (float*)(ws + off); off += (size_t)NP * 64 * 64 * 4;
    float* p4 = (float*)(ws + off); off += (size_t)NP * 32 * 32 * 4;
    float* t4 = (float*)(ws + off); off += (size_t)NP * 32 * 32 * 4;

    void* params[13] = {
        (void*)&pred, (void*)&targ,
        (void*)&p1, (void*)&t1, (void*)&p2, (void*)&t2,
        (void*)&p3, (void*)&t3, (void*)&p4, (void*)&t4,
        (void*)&kern, (void*)&accum, (void*)&out
    };
    hipError_t err = hipLaunchCooperativeKernel(
        reinterpret_cast<void*>(k_fused), dim3(1024), dim3(256), params, 0, stream);
    if (err != hipSuccess) {
        // fallback: same device code, 3-kernel rebalanced pipeline
        k_pool<<<1536, 256, 0, stream>>>(pred, targ, p1, t1, p2, t2, p3, t3, p4, t4, accum);
        k_ssim_all<<<1026, 256, 0, stream>>>(pred, targ, p1, t1, p2, t2, p3, t3,
                                             p4, t4, kern, accum);
        k_final<<<1, 1, 0, stream>>>(accum, out);
    }
}

// Round 2
// 232.393 us; speedup vs baseline: 3.2255x; 3.2255x over previous
//
#include <hip/hip_runtime.h>
#include <math.h>

#define NP 48   // 16 batch * 3 channels

typedef float v2f __attribute__((ext_vector_type(2)));

__device__ __forceinline__ float uniform_f(float v) {
    int i = __builtin_amdgcn_readfirstlane(__builtin_bit_cast(int, v));
    return __builtin_bit_cast(float, i);
}

// ---------------- sliding-window SSIM strip, LDS row staging ----------------
// R output rows per block-row-band; exact step count R+10 = CHF*22 + TAIL.
// Per step: 2 global loads/lane (+2 for 10 halo lanes) stage row rr+1 into the
// LDS double buffer while the h-blur of row rr reads conflict-free stride-1
// taps from the other buffer. One barrier per step. Frees the 44-reg tap
// array -> higher occupancy.
// rows layout: rows[0..1] = P double-buffer, rows[2..3] = T double-buffer.
template<int CHF, int TAIL, int R>
__device__ __forceinline__ void ssim_scale(
        const float* __restrict__ P, const float* __restrict__ T,
        int H, int sh, int lb, int scale, int slotsel, int tid,
        const float* __restrict__ k2d, double* __restrict__ accum,
        float (*__restrict__ rows)[272])
{
    // normalized 1D gaussian from center row of 2D kernel, pinned to SGPRs
    float w[11];
    {
        float s = 0.f;
#pragma unroll
        for (int i = 0; i < 11; ++i) s += k2d[55 + i];
        float inv = 1.0f / s;
#pragma unroll
        for (int i = 0; i < 11; ++i) w[i] = uniform_f(k2d[55 + i] * inv);
    }

    int blocksX = (NP << sh) >> 8;          // 48*H / 256
    int bxi = lb % blocksX;
    int by  = lb / blocksX;
    int g0  = bxi << 8;
    int g   = g0 + tid;
    int pl  = g >> sh;
    int x   = g & (H - 1);
    int yb  = by * R;

    // masked weights: zero taps falling outside this lane's plane row
    float wz[11];
#pragma unroll
    for (int j = 0; j < 11; ++j) {
        int c = x - 5 + j;
        wz[j] = (c >= 0 && c < H) ? w[j] : 0.f;
    }

    int HH   = H * H;
    int Cown = pl * HH + x;                 // per-lane column base (plane,col)
    // halo: lanes 0-4 -> left 5 cells, lanes 5-9 -> right 5 cells
    int gmax = (NP << sh) - 1;
    int gh   = (tid < 5) ? (g0 - 5 + tid) : (g0 + 256 + (tid - 5));
    gh = gh < 0 ? 0 : (gh > gmax ? gmax : gh);
    int Chalo = (gh >> sh) * HH + (gh & (H - 1));
    int hidx  = (tid < 5) ? tid : (256 + tid);   // lds halo cell
    bool is_halo = tid < 10;

    v2f wmu[11], we[11];
    float wpt[11];
    const float C1 = 1e-4f, C2 = 9e-4f;
    float lsum = 0.f, csum = 0.f;
    int rr = yb - 5;                        // compute row of step 0

    // preload step-0 row (clamped; vertical zero-pad handled by rr guard)
    {
        int nr = rr < 0 ? 0 : rr;
        int ro = nr * H;
        rows[0][5 + tid] = P[Cown + ro];
        rows[2][5 + tid] = T[Cown + ro];
        if (is_halo) {
            rows[0][hidx] = P[Chalo + ro];
            rows[2][hidx] = T[Chalo + ro];
        }
        __syncthreads();
    }

#define SSIM_STEP(PH)                                                          \
    {                                                                          \
        const int cb = (PH) & 1;            /* compile-time buffer parity */   \
        const int sl = (PH) % 11;           /* compile-time window slot   */   \
        /* issue global prefetch of row rr+1 (clamped address) */              \
        int nr = rr + 1;                                                       \
        nr = nr < 0 ? 0 : nr;                                                  \
        nr = nr > H - 1 ? H - 1 : nr;                                          \
        int ro = nr * H;                                                       \
        float vp = P[Cown + ro], vt = T[Cown + ro];                            \
        float hp = 0.f, ht = 0.f;                                              \
        if (is_halo) { hp = P[Chalo + ro]; ht = T[Chalo + ro]; }               \
        /* h-blur of row rr from LDS buffer cb (stride-1, conflict-free) */    \
        v2f a_mu = (v2f){0.f, 0.f};                                            \
        v2f a_e  = (v2f){0.f, 0.f};                                            \
        float apt = 0.f;                                                       \
        if (rr >= 0 && rr < H) {            /* uniform guard */                \
            _Pragma("unroll")                                                  \
            for (int j = 0; j < 11; ++j) {                                     \
                float pj = rows[cb][tid + j];                                  \
                float tj = rows[2 + cb][tid + j];                              \
                v2f pt2 = (v2f){pj, tj};                                       \
                v2f wv  = (v2f){wz[j], wz[j]};                                 \
                v2f wp2 = wv * pt2;                                            \
                a_mu += wp2;                                                   \
                a_e  += wp2 * pt2;                                             \
                apt = fmaf(wp2.x, tj, apt);    /* sum(w p t) */                \
            }                                                                  \
        }                                                                      \
        wmu[sl] = a_mu; we[sl] = a_e; wpt[sl] = apt;                           \
        if (rr >= yb + 5) {                 /* emit output row rr-5 */         \
            v2f mu2 = (v2f){0.f, 0.f};                                         \
            v2f e2  = (v2f){0.f, 0.f};                                         \
            float ept = 0.f;                                                   \
            _Pragma("unroll")                                                  \
            for (int i = 0; i < 11; ++i) {                                     \
                const int ss = (sl + 1 + i) % 11;   /* compile-time */         \
                v2f wi = (v2f){w[i], w[i]};         /* SGPR broadcast */       \
                mu2 += wi * wmu[ss];                                           \
                e2  += wi * we[ss];                                            \
                ept = fmaf(w[i], wpt[ss], ept);                                \
            }                                                                  \
            float m11 = mu2.x * mu2.x, m22 = mu2.y * mu2.y, m12 = mu2.x * mu2.y; \
            float s1  = fmaxf(e2.x - m11, 0.f);                                \
            float s2  = fmaxf(e2.y - m22, 0.f);                                \
            float s12 = ept - m12;                                             \
            lsum += (2.f * m12 + C1) * __builtin_amdgcn_rcpf(m11 + m22 + C1);  \
            csum += (2.f * s12 + C2) * __builtin_amdgcn_rcpf(s1 + s2 + C2);    \
        }                                                                      \
        /* write prefetched row into the other buffer (load latency hidden */  \
        /* under the compute above), then one barrier */                       \
        rows[cb ^ 1][5 + tid] = vp;                                            \
        rows[2 + (cb ^ 1)][5 + tid] = vt;                                      \
        if (is_halo) { rows[cb ^ 1][hidx] = hp; rows[2 + (cb ^ 1)][hidx] = ht; } \
        __syncthreads();                                                       \
        rr++;                                                                  \
    }

#pragma unroll 1
    for (int ch = 0; ch < CHF; ++ch) {
#pragma unroll
        for (int ph = 0; ph < 22; ++ph) SSIM_STEP(ph)
    }
#pragma unroll
    for (int ph = 0; ph < TAIL; ++ph) SSIM_STEP(ph)
#undef SSIM_STEP

    // wave shuffle reduce then cross-wave via LDS
#pragma unroll
    for (int o = 32; o > 0; o >>= 1) {
        lsum += __shfl_down(lsum, o, 64);
        csum += __shfl_down(csum, o, 64);
    }
    __shared__ float red[8];
    int wv = tid >> 6;
    if ((tid & 63) == 0) { red[2 * wv] = lsum; red[2 * wv + 1] = csum; }
    __syncthreads();
    if (tid == 0) {
        int slot = (scale * 8 + slotsel) * 2;
        atomicAdd(&accum[slot],     (double)(red[0] + red[2] + red[4] + red[6]));
        atomicAdd(&accum[slot + 1], (double)(red[1] + red[3] + red[5] + red[7]));
    }
}

// ---------------- pool job: 64x64 s1 tile; all scales from s0 ----------------
__device__ __forceinline__ void pool_job(int b, int tid,
        const float* __restrict__ pred, const float* __restrict__ targ,
        float* __restrict__ p1, float* __restrict__ t1,
        float* __restrict__ p2, float* __restrict__ t2,
        float* __restrict__ p3, float* __restrict__ t3,
        float* __restrict__ p4, float* __restrict__ t4)
{
    int pi   = b >> 4;          // 0..95 plane-image
    int tile = b & 15;          // 4x4 tiles over the 256x256 s1 plane
    int pls  = pi < 48 ? pi : pi - 48;
    const float* src = (pi < 48 ? pred : targ) + (size_t)pls * 512 * 512;
    float* d1 = (pi < 48 ? p1 : t1) + (size_t)pls * 256 * 256;
    float* d2 = (pi < 48 ? p2 : t2) + (size_t)pls * 128 * 128;
    float* d3 = (pi < 48 ? p3 : t3) + (size_t)pls * 64 * 64;
    float* d4 = (pi < 48 ? p4 : t4) + (size_t)pls * 32 * 32;
    int tY = tile >> 2, tX = tile & 3;
    int ty = tid >> 4, tx = tid & 15;
    int gy0 = tY * 128 + ty * 8, gx0 = tX * 128 + tx * 8;

    float s1v[4][4];
#pragma unroll
    for (int i = 0; i < 4; ++i) {
        const float* r0 = src + (size_t)(gy0 + 2 * i) * 512 + gx0;
        const float* r1 = r0 + 512;
        float4 a0 = *(const float4*)r0, a1 = *(const float4*)(r0 + 4);
        float4 b0 = *(const float4*)r1, b1 = *(const float4*)(r1 + 4);
        s1v[i][0] = 0.25f * ((a0.x + a0.y) + (b0.x + b0.y));
        s1v[i][1] = 0.25f * ((a0.z + a0.w) + (b0.z + b0.w));
        s1v[i][2] = 0.25f * ((a1.x + a1.y) + (b1.x + b1.y));
        s1v[i][3] = 0.25f * ((a1.z + a1.w) + (b1.z + b1.w));
        *(float4*)(d1 + (size_t)(tY * 64 + ty * 4 + i) * 256 + tX * 64 + tx * 4) =
            *(float4*)s1v[i];
    }
    float s2v[2][2];
#pragma unroll
    for (int i = 0; i < 2; ++i) {
#pragma unroll
        for (int j = 0; j < 2; ++j)
            s2v[i][j] = 0.25f * ((s1v[2*i][2*j] + s1v[2*i][2*j+1]) +
                                 (s1v[2*i+1][2*j] + s1v[2*i+1][2*j+1]));
        *(float2*)(d2 + (size_t)(tY * 32 + ty * 2 + i) * 128 + tX * 32 + tx * 2) =
            *(float2*)s2v[i];
    }
    float s3 = 0.25f * ((s2v[0][0] + s2v[0][1]) + (s2v[1][0] + s2v[1][1]));
    d3[(size_t)(tY * 16 + ty) * 64 + tX * 16 + tx] = s3;
    float v1 = s3 + __shfl_xor(s3, 1, 64);
    float v2 = v1 + __shfl_xor(v1, 16, 64);
    if ((ty & 1) == 0 && (tx & 1) == 0)
        d4[(size_t)(tY * 8 + (ty >> 1)) * 32 + tX * 8 + (tx >> 1)] = 0.25f * v2;
}

// ---------------- kernel A: scale-0 ssim strips FIRST (long poles), pools after ----
__global__ __launch_bounds__(256) void k_A(
        const float* __restrict__ pred, const float* __restrict__ targ,
        float* __restrict__ p1, float* __restrict__ t1,
        float* __restrict__ p2, float* __restrict__ t2,
        float* __restrict__ p3, float* __restrict__ t3,
        float* __restrict__ p4, float* __restrict__ t4,
        const float* __restrict__ k2d, double* __restrict__ accum)
{
    __shared__ float rows[4][272];
    int b   = blockIdx.x;
    int tid = threadIdx.x;
    if (b < 768) {
        // scale 0: H=512, 96 blocksX * 8 row-bands of 64 rows
        ssim_scale<3, 8, 64>(pred, targ, 512, 9, b, 0, b & 7, tid, k2d, accum, rows);
    } else {
        pool_job(b - 768, tid, pred, targ, p1, t1, p2, t2, p3, t3, p4, t4);
    }
}

// ---------------- kernel B: scales 1-4, 258 equal-cost jobs, fully parallel ----
__global__ __launch_bounds__(256) void k_B(
        const float* __restrict__ p1, const float* __restrict__ t1,
        const float* __restrict__ p2, const float* __restrict__ t2,
        const float* __restrict__ p3, const float* __restrict__ t3,
        const float* __restrict__ p4, const float* __restrict__ t4,
        const float* __restrict__ k2d, double* __restrict__ accum)
{
    __shared__ float rows[4][272];
    int b   = blockIdx.x;
    int tid = threadIdx.x;
    if (b < 192)      ssim_scale<3, 8, 64>(p1, t1, 256, 8, b,       1, b & 7, tid, k2d, accum, rows);
    else if (b < 240) ssim_scale<3, 8, 64>(p2, t2, 128, 7, b - 192, 2, b & 7, tid, k2d, accum, rows);
    else if (b < 252) ssim_scale<3, 8, 64>(p3, t3, 64,  6, b - 240, 3, b & 7, tid, k2d, accum, rows);
    else              ssim_scale<1, 20, 32>(p4, t4, 32, 5, b - 252, 4, b & 7, tid, k2d, accum, rows);
}

// ---------------- finalize: weighted power product ----------------
__global__ void k_final(const double* __restrict__ accum, float* __restrict__ out) {
    if (threadIdx.x != 0 || blockIdx.x != 0) return;
    const float wts[5] = {0.0448f, 0.2856f, 0.3001f, 0.2363f, 0.1333f};
    float ms = 1.0f;
    int Hs = 512;
    for (int s = 0; s < 5; ++s) {
        double lt = 0.0, ct = 0.0;
        for (int k = 0; k < 8; ++k) {
            lt += accum[(s * 8 + k) * 2];
            ct += accum[(s * 8 + k) * 2 + 1];
        }
        float N  = 48.0f * (float)Hs * (float)Hs;
        float l  = (float)lt / N;
        float cs = fmaxf((float)ct / N, 1e-8f);
        if (s == 4) {
            l = fmaxf(l, 1e-8f);
            ms *= powf(l, wts[s]) * powf(cs, wts[s]);
        } else {
            ms *= powf(cs, wts[s]);
        }
        Hs >>= 1;
    }
    out[0] = ms;
}

extern "C" void kernel_launch(void* const* d_in, const int* in_sizes, int n_in,
                              void* d_out, int out_size, void* d_ws, size_t ws_size,
                              hipStream_t stream) {
    const float* pred = (const float*)d_in[0];
    const float* targ = (const float*)d_in[1];
    const float* kern = (const float*)d_in[2];
    float* out = (float*)d_out;

    char* ws = (char*)d_ws;
    double* accum = (double*)ws;             // 80 doubles (5 scales * 8 slots * 2)
    size_t off = 1024;
    float* p1 = (float*)(ws + off); off += (size_t)NP * 256 * 256 * 4;
    float* t1 = (float*)(ws + off); off += (size_t)NP * 256 * 256 * 4;
    float* p2 = (float*)(ws + off); off += (size_t)NP * 128 * 128 * 4;
    float* t2 = (float*)(ws + off); off += (size_t)NP * 128 * 128 * 4;
    float* p3 = (float*)(ws + off); off += (size_t)NP * 64 * 64 * 4;
    float* t3 = (float*)(ws + off); off += (size_t)NP * 64 * 64 * 4;
    float* p4 = (float*)(ws + off); off += (size_t)NP * 32 * 32 * 4;
    float* t4 = (float*)(ws + off); off += (size_t)NP * 32 * 32 * 4;

    hipMemsetAsync(accum, 0, 640, stream);
    k_A<<<2304, 256, 0, stream>>>(pred, targ, p1, t1, p2, t2, p3, t3, p4, t4, kern, accum);
    k_B<<<258, 256, 0, stream>>>(p1, t1, p2, t2, p3, t3, p4, t4, kern, accum);
    k_final<<<1, 1, 0, stream>>>(accum, out);
}